// Round 1
// 608.019 us; speedup vs baseline: 1.0840x; 1.0840x over previous
//
#include <hip/hip_runtime.h>
#include <cstdint>
#include <cstddef>

// Problem constants (G=2,S=1024,D=2048,E=8,K=2)
#define DHID 2048
#define NEXP 8
#define NTOK 2048            // G*S tokens
#define NPAIR 4096           // NTOK*K routed pairs
#define NROWS 6144           // NPAIR + NTOK (shared expert appended)
#define MAXTILES 55          // worst-case routed m-tiles (39) + shared (16)
#define DD ((size_t)DHID * DHID)

typedef __attribute__((ext_vector_type(8))) __bf16 bf16x8;
typedef __attribute__((ext_vector_type(4))) __bf16 bf16x4;
typedef __attribute__((ext_vector_type(4))) float f32x4;

typedef __attribute__((address_space(3))) void lds_void;
typedef __attribute__((address_space(1))) void gbl_void;

__device__ __forceinline__ void gload16(const void* g, void* l) {
  __builtin_amdgcn_global_load_lds((gbl_void*)g, (lds_void*)l, 16, 0, 0);
}

// ---------------- routing: bucket pairs by expert, append shared pseudo-expert,
// ---------------- build (expert, m0) tile list for flattened GEMM grids -------
__global__ void route_kernel(const int* __restrict__ idx, const float* __restrict__ wts,
                             int* __restrict__ tok_id, float* __restrict__ tok_w,
                             int* __restrict__ dst_id,
                             int* __restrict__ cnts, int* __restrict__ offs,
                             int2* __restrict__ tiles) {
  __shared__ int c[NEXP];
  __shared__ int cur[NEXP];
  const int t = threadIdx.x;
  if (t < NEXP) c[t] = 0;
  __syncthreads();
  for (int p = t; p < NPAIR; p += 256) atomicAdd(&c[idx[p]], 1);
  __syncthreads();
  if (t == 0) {
    int run = 0;
    for (int e = 0; e < NEXP; ++e) { cur[e] = run; offs[e] = run; cnts[e] = c[e]; run += c[e]; }
    offs[NEXP] = NPAIR; cnts[NEXP] = NTOK;
    int nt = 0;
    for (int e = 0; e <= NEXP; ++e) {
      const int ce = (e < NEXP) ? c[e] : NTOK;
      for (int m0 = 0; m0 < ce; m0 += 128) { tiles[nt].x = e; tiles[nt].y = m0; ++nt; }
    }
    for (; nt < MAXTILES; ++nt) { tiles[nt].x = -1; tiles[nt].y = 0; }
  }
  __syncthreads();
  for (int p = t; p < NPAIR; p += 256) {
    const int e = idx[p];
    const int slot = atomicAdd(&cur[e], 1);
    tok_id[slot] = p >> 1;          // K=2: token = pair/2 (flat g*S+s)
    tok_w[slot] = wts[p];
    dst_id[slot] = p;               // pair-slot row in combine buffer
  }
  for (int i = t; i < NTOK; i += 256) {
    tok_id[NPAIR + i] = i; tok_w[NPAIR + i] = 1.0f; dst_id[NPAIR + i] = NPAIR + i;
  }
}

// ---------------- fused f32 -> bf16 cast of ALL tensors (one dispatch) --------
// Unit-stride everywhere: float4 f -> bf16x4 chunk f (identity index map).
// Thread t of block b handles f = b*512 + t and f + 256.
// f32 sources are streamed ONCE -> nontemporal loads keep LLC free for the
// bf16 weights (which the GEMMs re-read 4-5x).
// dst linear layout (f4 units, L4 = DD/4): gw(8L4) sgw(L4) uw(8L4) suw(L4)
// dwn(8L4) sdw(L4) x(L4) = 28*L4 = 29360128 f4 = 57344 blocks * 512.
__global__ void cast_all_kernel(const f32x4* __restrict__ gw, const f32x4* __restrict__ sgw,
                                const f32x4* __restrict__ uw, const f32x4* __restrict__ suw,
                                const f32x4* __restrict__ dwn, const f32x4* __restrict__ sdw,
                                const f32x4* __restrict__ x, bf16x4* __restrict__ dst) {
  const size_t L4 = DD / 4;
  const size_t base = (size_t)blockIdx.x * 512 + threadIdx.x;
#pragma unroll
  for (int half = 0; half < 2; ++half) {
    const size_t f = base + (size_t)half * 256;
    size_t r = f;
    const f32x4* src;
    if (r < 8 * L4) { src = gw; }
    else if ((r -= 8 * L4) < L4) { src = sgw; }
    else if ((r -= L4) < 8 * L4) { src = uw; }
    else if ((r -= 8 * L4) < L4) { src = suw; }
    else if ((r -= L4) < 8 * L4) { src = dwn; }
    else if ((r -= 8 * L4) < L4) { src = sdw; }
    else { r -= L4; src = x; }
    const f32x4 a = __builtin_nontemporal_load(src + r);
    bf16x4 o;
    o[0] = (__bf16)a[0]; o[1] = (__bf16)a[1]; o[2] = (__bf16)a[2]; o[3] = (__bf16)a[3];
    dst[f] = o;
  }
}

// ---------------- fused gate+up grouped GEMM + SiLU ---------------------------
// Block tile 128(m) x 64(n), BK=64. 4 waves, wave tile 64x32.
// acc = 2 outputs x 4x2 f32x4 = 64 AGPR/wave -> 3 blocks/CU.
__global__ __launch_bounds__(256, 3) void gateup_kernel(
    const __bf16* __restrict__ xb,
    const __bf16* __restrict__ wbg, const __bf16* __restrict__ wbu,
    __bf16* __restrict__ act,
    const int* __restrict__ tok_id,
    const int* __restrict__ cnts, const int* __restrict__ offs,
    const int2* __restrict__ tiles) {
  const int2 tl = tiles[blockIdx.y];
  const int e = tl.x;
  if (e < 0) return;
  const int m0 = tl.y;
  const int cnt = cnts[e];
  const int n0 = blockIdx.x * 64;
  const int off = offs[e];
  const __bf16* Bg = wbg + (size_t)e * DD;
  const __bf16* Bu = wbu + (size_t)e * DD;

  __shared__ __align__(16) char sA[128 * 64 * 2];   // 16 KB: bf16 [128][64]
  __shared__ __align__(16) char sBg[64 * 64 * 2];   // 8 KB
  __shared__ __align__(16) char sBu[64 * 64 * 2];   // 8 KB

  const int tid = threadIdx.x;
  const int lane = tid & 63;
  const int wv = tid >> 6;
  const int mw = (wv >> 1) * 64;
  const int nw = (wv & 1) * 32;
  const int q4 = lane >> 4;
  const int ln = lane & 15;

  // Staging: chunk q = tid + j*256 -> row q>>3 (A: [0,128), B: [0,64)),
  // LDS dest is LINEAR (q*16); the GLOBAL source part is permuted:
  // part p = (tid&7) ^ ((tid>>3)&7)  (row&7 invariant across j since rows step by 32)
  const int rbase = tid >> 3;
  const int part = (tid & 7) ^ (rbase & 7);

  const char* gA[4];
#pragma unroll
  for (int j = 0; j < 4; ++j) {
    int r = m0 + rbase + 32 * j;
    r = (r < cnt) ? r : (cnt - 1);
    gA[j] = (const char*)(xb + (size_t)tok_id[off + r] * DHID) + part * 16;
  }
  const char* gBg[2]; const char* gBu[2];
#pragma unroll
  for (int j = 0; j < 2; ++j) {
    gBg[j] = (const char*)(Bg + (size_t)(n0 + rbase + 32 * j) * DHID) + part * 16;
    gBu[j] = (const char*)(Bu + (size_t)(n0 + rbase + 32 * j) * DHID) + part * 16;
  }

  f32x4 accg[4][2], accu[4][2];
  const f32x4 vz = {0.f, 0.f, 0.f, 0.f};
#pragma unroll
  for (int i = 0; i < 4; ++i)
#pragma unroll
    for (int j = 0; j < 2; ++j) { accg[i][j] = vz; accu[i][j] = vz; }

  for (int kt = 0; kt < DHID; kt += 64) {
#pragma unroll
    for (int j = 0; j < 4; ++j)
      gload16(gA[j] + (size_t)kt * 2, sA + (tid + j * 256) * 16);
#pragma unroll
    for (int j = 0; j < 2; ++j) {
      gload16(gBg[j] + (size_t)kt * 2, sBg + (tid + j * 256) * 16);
      gload16(gBu[j] + (size_t)kt * 2, sBu + (tid + j * 256) * 16);
    }
    __syncthreads();

#pragma unroll
    for (int h = 0; h < 2; ++h) {
      bf16x8 af[4];
#pragma unroll
      for (int im = 0; im < 4; ++im) {
        const int r = mw + im * 16 + ln;
        af[im] = *(const bf16x8*)(sA + ((r * 8 + ((q4 + 4 * h) ^ (r & 7))) << 4));
      }
#pragma unroll
      for (int in_ = 0; in_ < 2; ++in_) {
        const int r = nw + in_ * 16 + ln;
        const int c = (r * 8 + ((q4 + 4 * h) ^ (r & 7))) << 4;
        const bf16x8 bg = *(const bf16x8*)(sBg + c);
        const bf16x8 bu = *(const bf16x8*)(sBu + c);
#pragma unroll
        for (int im = 0; im < 4; ++im) {
          accg[im][in_] = __builtin_amdgcn_mfma_f32_16x16x32_bf16(af[im], bg, accg[im][in_], 0, 0, 0);
          accu[im][in_] = __builtin_amdgcn_mfma_f32_16x16x32_bf16(af[im], bu, accu[im][in_], 0, 0, 0);
        }
      }
    }
    __syncthreads();
  }

  // epilogue: act = silu(gate) * up -> bf16
#pragma unroll
  for (int im = 0; im < 4; ++im) {
#pragma unroll
    for (int rr = 0; rr < 4; ++rr) {
      const int row = mw + im * 16 + q4 * 4 + rr;
      if (m0 + row < cnt) {
        __bf16* dst = act + (size_t)(off + m0 + row) * DHID + n0 + nw + ln;
#pragma unroll
        for (int in_ = 0; in_ < 2; ++in_) {
          const float gg = accg[im][in_][rr];
          const float uu = accu[im][in_][rr];
          const float a = (gg / (1.0f + __expf(-gg))) * uu;
          dst[in_ * 16] = (__bf16)a;
        }
      }
    }
  }
}

// ---------------- down grouped GEMM, weighted write to pair-slot buffer -------
// Block tile 128(m) x 128(n), BK=64 (m97-proven optimum shape).
// 4 waves, wave tile 64x64, acc 4x4 f32x4 = 64 AGPR/wave -> 3 blocks/CU.
__global__ __launch_bounds__(256, 3) void down_kernel(
    const __bf16* __restrict__ act,
    const __bf16* __restrict__ wbd,
    float* __restrict__ buf,
    const float* __restrict__ tok_w, const int* __restrict__ dst_id,
    const int* __restrict__ cnts, const int* __restrict__ offs,
    const int2* __restrict__ tiles) {
  const int2 tl = tiles[blockIdx.y];
  const int e = tl.x;
  if (e < 0) return;
  const int m0 = tl.y;
  const int cnt = cnts[e];
  const int n0 = blockIdx.x * 128;
  const int off = offs[e];
  const __bf16* B = wbd + (size_t)e * DD;

  __shared__ __align__(16) char sA[128 * 64 * 2];   // 16 KB
  __shared__ __align__(16) char sB[128 * 64 * 2];   // 16 KB

  const int tid = threadIdx.x;
  const int lane = tid & 63;
  const int wv = tid >> 6;
  const int mw = (wv >> 1) * 64;
  const int nw = (wv & 1) * 64;
  const int q4 = lane >> 4;
  const int ln = lane & 15;

  const int rbase = tid >> 3;
  const int part = (tid & 7) ^ (rbase & 7);

  const char* gA[4];
  const char* gB[4];
#pragma unroll
  for (int j = 0; j < 4; ++j) {
    gA[j] = (const char*)(act + (size_t)(off + m0 + rbase + 32 * j) * DHID) + part * 16;
    gB[j] = (const char*)(B + (size_t)(n0 + rbase + 32 * j) * DHID) + part * 16;
  }

  f32x4 acc[4][4];
  const f32x4 vz = {0.f, 0.f, 0.f, 0.f};
#pragma unroll
  for (int i = 0; i < 4; ++i)
#pragma unroll
    for (int j = 0; j < 4; ++j) acc[i][j] = vz;

  for (int kt = 0; kt < DHID; kt += 64) {
#pragma unroll
    for (int j = 0; j < 4; ++j) {
      gload16(gA[j] + (size_t)kt * 2, sA + (tid + j * 256) * 16);
      gload16(gB[j] + (size_t)kt * 2, sB + (tid + j * 256) * 16);
    }
    __syncthreads();

#pragma unroll
    for (int h = 0; h < 2; ++h) {
      bf16x8 af[4], bfr[4];
#pragma unroll
      for (int im = 0; im < 4; ++im) {
        const int r = mw + im * 16 + ln;
        af[im] = *(const bf16x8*)(sA + ((r * 8 + ((q4 + 4 * h) ^ (r & 7))) << 4));
      }
#pragma unroll
      for (int in_ = 0; in_ < 4; ++in_) {
        const int r = nw + in_ * 16 + ln;
        bfr[in_] = *(const bf16x8*)(sB + ((r * 8 + ((q4 + 4 * h) ^ (r & 7))) << 4));
      }
#pragma unroll
      for (int in_ = 0; in_ < 4; ++in_)
#pragma unroll
        for (int im = 0; im < 4; ++im)
          acc[im][in_] = __builtin_amdgcn_mfma_f32_16x16x32_bf16(af[im], bfr[in_], acc[im][in_], 0, 0, 0);
    }
    __syncthreads();
  }

#pragma unroll
  for (int im = 0; im < 4; ++im) {
#pragma unroll
    for (int rr = 0; rr < 4; ++rr) {
      const int row = mw + im * 16 + q4 * 4 + rr;
      if (m0 + row < cnt) {
        const int gr = off + m0 + row;
        const float wt = tok_w[gr];
        float* dst = buf + (size_t)dst_id[gr] * DHID + n0 + nw + ln;
#pragma unroll
        for (int in_ = 0; in_ < 4; ++in_)
          dst[in_ * 16] = wt * acc[im][in_][rr];
      }
    }
  }
}

// ---------------- combine: out[t] = buf[2t] + buf[2t+1] + buf[NPAIR+t] --------
__global__ void combine_kernel(const float4* __restrict__ buf, float4* __restrict__ out) {
  const int i = blockIdx.x * 256 + threadIdx.x;   // over NTOK*DHID/4 = 1M
  const int t = i >> 9;                           // DHID/4 = 512 float4 per row
  const int d = i & 511;
  const float4 a = buf[(size_t)(2 * t) * 512 + d];
  const float4 b = buf[(size_t)(2 * t + 1) * 512 + d];
  const float4 c = buf[(size_t)(NPAIR + t) * 512 + d];
  float4 r;
  r.x = a.x + b.x + c.x; r.y = a.y + b.y + c.y;
  r.z = a.z + b.z + c.z; r.w = a.w + b.w + c.w;
  out[i] = r;
}

extern "C" void kernel_launch(void* const* d_in, const int* in_sizes, int n_in,
                              void* d_out, int out_size, void* d_ws, size_t ws_size,
                              hipStream_t stream) {
  (void)in_sizes; (void)n_in; (void)out_size; (void)ws_size;
  const float* x   = (const float*)d_in[0];
  const float* wts = (const float*)d_in[1];
  const int*   idx = (const int*)d_in[2];
  const float* gw  = (const float*)d_in[5];
  const float* uw  = (const float*)d_in[6];
  const float* dwn = (const float*)d_in[7];
  const float* sgw = (const float*)d_in[8];
  const float* suw = (const float*)d_in[9];
  const float* sdw = (const float*)d_in[10];
  float* out = (float*)d_out;
  char* ws = (char*)d_ws;

  // ws layout (~296.1 MiB):
  //   [0)        wbg bf16 [9][DD]   (8 experts + shared)   72 MiB
  //   wbu, wbd   same                                      144 MiB
  //   xb  bf16 [NTOK][DHID]                                8 MiB
  //   act bf16 [NROWS][DHID]                               24 MiB
  //   buf f32  [NROWS][DHID]                               48 MiB
  //   route tables                                         128 KiB
  const size_t WB    = 3 * 9 * DD * 2;
  const size_t XBsz  = (size_t)NTOK * DHID * 2;
  const size_t ACTsz = (size_t)NROWS * DHID * 2;
  const size_t BUFsz = (size_t)NROWS * DHID * 4;

  __bf16* wbg = (__bf16*)ws;
  __bf16* wbu = wbg + 9 * DD;
  __bf16* wbd = wbu + 9 * DD;
  __bf16* xb  = (__bf16*)(ws + WB);
  __bf16* act = (__bf16*)(ws + WB + XBsz);
  float*  buf = (float*)(ws + WB + XBsz + ACTsz);
  char*   rt  = ws + WB + XBsz + ACTsz + BUFsz;
  int*   tok_id = (int*)rt;
  float* tok_w  = (float*)(rt + NROWS * 4);
  int*   dst_id = (int*)(rt + NROWS * 8);
  int*   cnts   = (int*)(rt + NROWS * 12);
  int*   offs   = cnts + 16;
  int2*  tiles  = (int2*)(offs + 16);

  route_kernel<<<1, 256, 0, stream>>>(idx, wts, tok_id, tok_w, dst_id, cnts, offs, tiles);
  // dst order matches ws layout: [gw|sgw][uw|suw][dwn|sdw][x]
  cast_all_kernel<<<57344, 256, 0, stream>>>((const f32x4*)gw, (const f32x4*)sgw,
                                             (const f32x4*)uw, (const f32x4*)suw,
                                             (const f32x4*)dwn, (const f32x4*)sdw,
                                             (const f32x4*)x, (bf16x4*)ws);
  gateup_kernel<<<dim3(32, MAXTILES), 256, 0, stream>>>(
      xb, wbg, wbu, act, tok_id, cnts, offs, tiles);
  down_kernel<<<dim3(16, MAXTILES), 256, 0, stream>>>(
      act, wbd, buf, tok_w, dst_id, cnts, offs, tiles);
  combine_kernel<<<4096, 256, 0, stream>>>((const float4*)buf, (float4*)out);
}

// Round 2
// 567.894 us; speedup vs baseline: 1.1606x; 1.0707x over previous
//
#include <hip/hip_runtime.h>
#include <cstdint>
#include <cstddef>

// Problem constants (G=2,S=1024,D=2048,E=8,K=2)
#define DHID 2048
#define NEXP 8
#define NTOK 2048            // G*S tokens
#define NPAIR 4096           // NTOK*K routed pairs
#define NROWS 6144           // NPAIR + NTOK (shared expert appended)
#define MAXTILES 55          // worst-case routed m-tiles (39) + shared (16)
#define CASTY 144            // appended cast rows in gateup grid (144*32 blocks)
#define DD ((size_t)DHID * DHID)

typedef __attribute__((ext_vector_type(8))) __bf16 bf16x8;
typedef __attribute__((ext_vector_type(4))) __bf16 bf16x4;
typedef __attribute__((ext_vector_type(4))) float f32x4;

typedef __attribute__((address_space(3))) void lds_void;
typedef __attribute__((address_space(1))) void gbl_void;

__device__ __forceinline__ void gload16(const void* g, void* l) {
  __builtin_amdgcn_global_load_lds((gbl_void*)g, (lds_void*)l, 16, 0, 0);
}

// ---------------- front kernel: route (block 0) + cast of gateup inputs ------
// Cast covers gw(8L4) sgw(L4) uw(8L4) suw(L4) x(L4->dst 27L4) = 19L4 f4 chunks,
// 512 f4 per block -> 38912 cast blocks (+1 route block). Unit-stride f32x4
// loads -> bf16x4 stores (identity index map, no shuffle).
// The dwn/sdw cast (216 MB, ~37us of BW) is NOT here: it rides inside
// gateup_kernel's spare HBM bandwidth (gateup is compute-bound).
__global__ void cast_route_kernel(
    const f32x4* __restrict__ gw, const f32x4* __restrict__ sgw,
    const f32x4* __restrict__ uw, const f32x4* __restrict__ suw,
    const f32x4* __restrict__ x, bf16x4* __restrict__ dst,
    const int* __restrict__ idx, const float* __restrict__ wts,
    int* __restrict__ tok_id, float* __restrict__ tok_w,
    int* __restrict__ dst_id,
    int* __restrict__ cnts, int* __restrict__ offs,
    int2* __restrict__ tiles) {
  if (blockIdx.x == 0) {
    // ---- routing: bucket pairs by expert, append shared pseudo-expert ----
    __shared__ int c[NEXP];
    __shared__ int cur[NEXP];
    const int t = threadIdx.x;
    if (t < NEXP) c[t] = 0;
    __syncthreads();
    for (int p = t; p < NPAIR; p += 256) atomicAdd(&c[idx[p]], 1);
    __syncthreads();
    if (t == 0) {
      int run = 0;
      for (int e = 0; e < NEXP; ++e) { cur[e] = run; offs[e] = run; cnts[e] = c[e]; run += c[e]; }
      offs[NEXP] = NPAIR; cnts[NEXP] = NTOK;
      int nt = 0;
      for (int e = 0; e <= NEXP; ++e) {
        const int ce = (e < NEXP) ? c[e] : NTOK;
        for (int m0 = 0; m0 < ce; m0 += 128) { tiles[nt].x = e; tiles[nt].y = m0; ++nt; }
      }
      for (; nt < MAXTILES; ++nt) { tiles[nt].x = -1; tiles[nt].y = 0; }
    }
    __syncthreads();
    for (int p = t; p < NPAIR; p += 256) {
      const int e = idx[p];
      const int slot = atomicAdd(&cur[e], 1);
      tok_id[slot] = p >> 1;          // K=2: token = pair/2 (flat g*S+s)
      tok_w[slot] = wts[p];
      dst_id[slot] = p;               // pair-slot row in combine buffer
    }
    for (int i = t; i < NTOK; i += 256) {
      tok_id[NPAIR + i] = i; tok_w[NPAIR + i] = 1.0f; dst_id[NPAIR + i] = NPAIR + i;
    }
    return;
  }
  // ---- cast: chunk space [0, 19L4) -> dst chunks (x remaps to 27L4+) ----
  const size_t L4 = DD / 4;
  const size_t base = (size_t)(blockIdx.x - 1) * 512 + threadIdx.x;
#pragma unroll
  for (int half = 0; half < 2; ++half) {
    const size_t f = base + (size_t)half * 256;
    size_t r = f;
    size_t d = f;
    const f32x4* src;
    if (r < 8 * L4) { src = gw; }
    else if ((r -= 8 * L4) < L4) { src = sgw; }
    else if ((r -= L4) < 8 * L4) { src = uw; }
    else if ((r -= 8 * L4) < L4) { src = suw; }
    else { r -= L4; src = x; d = 27 * L4 + r; }
    const f32x4 a = __builtin_nontemporal_load(src + r);
    bf16x4 o;
    o[0] = (__bf16)a[0]; o[1] = (__bf16)a[1]; o[2] = (__bf16)a[2]; o[3] = (__bf16)a[3];
    dst[d] = o;
  }
}

// ---------------- fused gate+up grouped GEMM + SiLU + down-weight cast --------
// GEMM rows (blockIdx.y < MAXTILES): block tile 128(m) x 64(n), BK=64,
// 4 waves, wave tile 64x32, acc 2x4x2 f32x4 = 64 AGPR/wave -> 3 blocks/CU.
// Cast rows (blockIdx.y >= MAXTILES): dwn(8L4)+sdw(L4) f32 -> wbd bf16,
// 2048 f4 per block, 4608 blocks. These launch after the GEMM blocks and
// backfill retiring slots, hiding ~37us of cast BW under GEMM compute.
__global__ __launch_bounds__(256, 3) void gateup_kernel(
    const __bf16* __restrict__ xb,
    const __bf16* __restrict__ wbg, const __bf16* __restrict__ wbu,
    __bf16* __restrict__ act,
    const int* __restrict__ tok_id,
    const int* __restrict__ cnts, const int* __restrict__ offs,
    const int2* __restrict__ tiles,
    const f32x4* __restrict__ dwn, const f32x4* __restrict__ sdw,
    bf16x4* __restrict__ castdst) {
  if (blockIdx.y >= MAXTILES) {
    const size_t L4 = DD / 4;
    const int cb = (blockIdx.y - MAXTILES) * 32 + blockIdx.x;
    const size_t base = (size_t)cb * 2048 + threadIdx.x;
#pragma unroll
    for (int j = 0; j < 8; ++j) {
      const size_t f = base + (size_t)j * 256;
      size_t r = f;
      const f32x4* src = dwn;
      if (r >= 8 * L4) { r -= 8 * L4; src = sdw; }
      const f32x4 a = __builtin_nontemporal_load(src + r);
      bf16x4 o;
      o[0] = (__bf16)a[0]; o[1] = (__bf16)a[1]; o[2] = (__bf16)a[2]; o[3] = (__bf16)a[3];
      castdst[18 * L4 + f] = o;   // wbd region starts at chunk 18*L4
    }
    return;
  }

  const int2 tl = tiles[blockIdx.y];
  const int e = tl.x;
  if (e < 0) return;
  const int m0 = tl.y;
  const int cnt = cnts[e];
  const int n0 = blockIdx.x * 64;
  const int off = offs[e];
  const __bf16* Bg = wbg + (size_t)e * DD;
  const __bf16* Bu = wbu + (size_t)e * DD;

  __shared__ __align__(16) char sA[128 * 64 * 2];   // 16 KB: bf16 [128][64]
  __shared__ __align__(16) char sBg[64 * 64 * 2];   // 8 KB
  __shared__ __align__(16) char sBu[64 * 64 * 2];   // 8 KB

  const int tid = threadIdx.x;
  const int lane = tid & 63;
  const int wv = tid >> 6;
  const int mw = (wv >> 1) * 64;
  const int nw = (wv & 1) * 32;
  const int q4 = lane >> 4;
  const int ln = lane & 15;

  // Staging: chunk q = tid + j*256 -> row q>>3 (A: [0,128), B: [0,64)),
  // LDS dest is LINEAR (q*16); the GLOBAL source part is permuted:
  // part p = (tid&7) ^ ((tid>>3)&7)  (row&7 invariant across j since rows step by 32)
  const int rbase = tid >> 3;
  const int part = (tid & 7) ^ (rbase & 7);

  const char* gA[4];
#pragma unroll
  for (int j = 0; j < 4; ++j) {
    int r = m0 + rbase + 32 * j;
    r = (r < cnt) ? r : (cnt - 1);
    gA[j] = (const char*)(xb + (size_t)tok_id[off + r] * DHID) + part * 16;
  }
  const char* gBg[2]; const char* gBu[2];
#pragma unroll
  for (int j = 0; j < 2; ++j) {
    gBg[j] = (const char*)(Bg + (size_t)(n0 + rbase + 32 * j) * DHID) + part * 16;
    gBu[j] = (const char*)(Bu + (size_t)(n0 + rbase + 32 * j) * DHID) + part * 16;
  }

  f32x4 accg[4][2], accu[4][2];
  const f32x4 vz = {0.f, 0.f, 0.f, 0.f};
#pragma unroll
  for (int i = 0; i < 4; ++i)
#pragma unroll
    for (int j = 0; j < 2; ++j) { accg[i][j] = vz; accu[i][j] = vz; }

  for (int kt = 0; kt < DHID; kt += 64) {
#pragma unroll
    for (int j = 0; j < 4; ++j)
      gload16(gA[j] + (size_t)kt * 2, sA + (tid + j * 256) * 16);
#pragma unroll
    for (int j = 0; j < 2; ++j) {
      gload16(gBg[j] + (size_t)kt * 2, sBg + (tid + j * 256) * 16);
      gload16(gBu[j] + (size_t)kt * 2, sBu + (tid + j * 256) * 16);
    }
    __syncthreads();

#pragma unroll
    for (int h = 0; h < 2; ++h) {
      bf16x8 af[4];
#pragma unroll
      for (int im = 0; im < 4; ++im) {
        const int r = mw + im * 16 + ln;
        af[im] = *(const bf16x8*)(sA + ((r * 8 + ((q4 + 4 * h) ^ (r & 7))) << 4));
      }
#pragma unroll
      for (int in_ = 0; in_ < 2; ++in_) {
        const int r = nw + in_ * 16 + ln;
        const int c = (r * 8 + ((q4 + 4 * h) ^ (r & 7))) << 4;
        const bf16x8 bg = *(const bf16x8*)(sBg + c);
        const bf16x8 bu = *(const bf16x8*)(sBu + c);
#pragma unroll
        for (int im = 0; im < 4; ++im) {
          accg[im][in_] = __builtin_amdgcn_mfma_f32_16x16x32_bf16(af[im], bg, accg[im][in_], 0, 0, 0);
          accu[im][in_] = __builtin_amdgcn_mfma_f32_16x16x32_bf16(af[im], bu, accu[im][in_], 0, 0, 0);
        }
      }
    }
    __syncthreads();
  }

  // epilogue: act = silu(gate) * up -> bf16
#pragma unroll
  for (int im = 0; im < 4; ++im) {
#pragma unroll
    for (int rr = 0; rr < 4; ++rr) {
      const int row = mw + im * 16 + q4 * 4 + rr;
      if (m0 + row < cnt) {
        __bf16* dst = act + (size_t)(off + m0 + row) * DHID + n0 + nw + ln;
#pragma unroll
        for (int in_ = 0; in_ < 2; ++in_) {
          const float gg = accg[im][in_][rr];
          const float uu = accu[im][in_][rr];
          const float a = (gg / (1.0f + __expf(-gg))) * uu;
          dst[in_ * 16] = (__bf16)a;
        }
      }
    }
  }
}

// ---------------- down grouped GEMM, weighted write to pair-slot buffer -------
// Block tile 128(m) x 128(n), BK=64 (m97-proven optimum shape).
// 4 waves, wave tile 64x64, acc 4x4 f32x4 = 64 AGPR/wave -> 3 blocks/CU.
__global__ __launch_bounds__(256, 3) void down_kernel(
    const __bf16* __restrict__ act,
    const __bf16* __restrict__ wbd,
    float* __restrict__ buf,
    const float* __restrict__ tok_w, const int* __restrict__ dst_id,
    const int* __restrict__ cnts, const int* __restrict__ offs,
    const int2* __restrict__ tiles) {
  const int2 tl = tiles[blockIdx.y];
  const int e = tl.x;
  if (e < 0) return;
  const int m0 = tl.y;
  const int cnt = cnts[e];
  const int n0 = blockIdx.x * 128;
  const int off = offs[e];
  const __bf16* B = wbd + (size_t)e * DD;

  __shared__ __align__(16) char sA[128 * 64 * 2];   // 16 KB
  __shared__ __align__(16) char sB[128 * 64 * 2];   // 16 KB

  const int tid = threadIdx.x;
  const int lane = tid & 63;
  const int wv = tid >> 6;
  const int mw = (wv >> 1) * 64;
  const int nw = (wv & 1) * 64;
  const int q4 = lane >> 4;
  const int ln = lane & 15;

  const int rbase = tid >> 3;
  const int part = (tid & 7) ^ (rbase & 7);

  const char* gA[4];
  const char* gB[4];
#pragma unroll
  for (int j = 0; j < 4; ++j) {
    gA[j] = (const char*)(act + (size_t)(off + m0 + rbase + 32 * j) * DHID) + part * 16;
    gB[j] = (const char*)(B + (size_t)(n0 + rbase + 32 * j) * DHID) + part * 16;
  }

  f32x4 acc[4][4];
  const f32x4 vz = {0.f, 0.f, 0.f, 0.f};
#pragma unroll
  for (int i = 0; i < 4; ++i)
#pragma unroll
    for (int j = 0; j < 4; ++j) acc[i][j] = vz;

  for (int kt = 0; kt < DHID; kt += 64) {
#pragma unroll
    for (int j = 0; j < 4; ++j) {
      gload16(gA[j] + (size_t)kt * 2, sA + (tid + j * 256) * 16);
      gload16(gB[j] + (size_t)kt * 2, sB + (tid + j * 256) * 16);
    }
    __syncthreads();

#pragma unroll
    for (int h = 0; h < 2; ++h) {
      bf16x8 af[4], bfr[4];
#pragma unroll
      for (int im = 0; im < 4; ++im) {
        const int r = mw + im * 16 + ln;
        af[im] = *(const bf16x8*)(sA + ((r * 8 + ((q4 + 4 * h) ^ (r & 7))) << 4));
      }
#pragma unroll
      for (int in_ = 0; in_ < 4; ++in_) {
        const int r = nw + in_ * 16 + ln;
        bfr[in_] = *(const bf16x8*)(sB + ((r * 8 + ((q4 + 4 * h) ^ (r & 7))) << 4));
      }
#pragma unroll
      for (int in_ = 0; in_ < 4; ++in_)
#pragma unroll
        for (int im = 0; im < 4; ++im)
          acc[im][in_] = __builtin_amdgcn_mfma_f32_16x16x32_bf16(af[im], bfr[in_], acc[im][in_], 0, 0, 0);
    }
    __syncthreads();
  }

#pragma unroll
  for (int im = 0; im < 4; ++im) {
#pragma unroll
    for (int rr = 0; rr < 4; ++rr) {
      const int row = mw + im * 16 + q4 * 4 + rr;
      if (m0 + row < cnt) {
        const int gr = off + m0 + row;
        const float wt = tok_w[gr];
        float* dst = buf + (size_t)dst_id[gr] * DHID + n0 + nw + ln;
#pragma unroll
        for (int in_ = 0; in_ < 4; ++in_)
          dst[in_ * 16] = wt * acc[im][in_][rr];
      }
    }
  }
}

// ---------------- combine: out[t] = buf[2t] + buf[2t+1] + buf[NPAIR+t] --------
__global__ void combine_kernel(const float4* __restrict__ buf, float4* __restrict__ out) {
  const int i = blockIdx.x * 256 + threadIdx.x;   // over NTOK*DHID/4 = 1M
  const int t = i >> 9;                           // DHID/4 = 512 float4 per row
  const int d = i & 511;
  const float4 a = buf[(size_t)(2 * t) * 512 + d];
  const float4 b = buf[(size_t)(2 * t + 1) * 512 + d];
  const float4 c = buf[(size_t)(NPAIR + t) * 512 + d];
  float4 r;
  r.x = a.x + b.x + c.x; r.y = a.y + b.y + c.y;
  r.z = a.z + b.z + c.z; r.w = a.w + b.w + c.w;
  out[i] = r;
}

extern "C" void kernel_launch(void* const* d_in, const int* in_sizes, int n_in,
                              void* d_out, int out_size, void* d_ws, size_t ws_size,
                              hipStream_t stream) {
  (void)in_sizes; (void)n_in; (void)out_size; (void)ws_size;
  const float* x   = (const float*)d_in[0];
  const float* wts = (const float*)d_in[1];
  const int*   idx = (const int*)d_in[2];
  const float* gw  = (const float*)d_in[5];
  const float* uw  = (const float*)d_in[6];
  const float* dwn = (const float*)d_in[7];
  const float* sgw = (const float*)d_in[8];
  const float* suw = (const float*)d_in[9];
  const float* sdw = (const float*)d_in[10];
  float* out = (float*)d_out;
  char* ws = (char*)d_ws;

  // ws layout (~296.1 MiB):
  //   [0)        wbg bf16 [9][DD]   (8 experts + shared)   72 MiB
  //   wbu, wbd   same                                      144 MiB
  //   xb  bf16 [NTOK][DHID]                                8 MiB
  //   act bf16 [NROWS][DHID]                               24 MiB
  //   buf f32  [NROWS][DHID]                               48 MiB
  //   route tables                                         128 KiB
  const size_t WB    = 3 * 9 * DD * 2;
  const size_t XBsz  = (size_t)NTOK * DHID * 2;
  const size_t ACTsz = (size_t)NROWS * DHID * 2;
  const size_t BUFsz = (size_t)NROWS * DHID * 4;

  __bf16* wbg = (__bf16*)ws;
  __bf16* wbu = wbg + 9 * DD;
  __bf16* wbd = wbu + 9 * DD;
  __bf16* xb  = (__bf16*)(ws + WB);
  __bf16* act = (__bf16*)(ws + WB + XBsz);
  float*  buf = (float*)(ws + WB + XBsz + ACTsz);
  char*   rt  = ws + WB + XBsz + ACTsz + BUFsz;
  int*   tok_id = (int*)rt;
  float* tok_w  = (float*)(rt + NROWS * 4);
  int*   dst_id = (int*)(rt + NROWS * 8);
  int*   cnts   = (int*)(rt + NROWS * 12);
  int*   offs   = cnts + 16;
  int2*  tiles  = (int2*)(offs + 16);

  // front: route (block 0) + cast of gateup inputs (19*L4 chunks / 512 = 38912 blocks)
  cast_route_kernel<<<38913, 256, 0, stream>>>(
      (const f32x4*)gw, (const f32x4*)sgw, (const f32x4*)uw, (const f32x4*)suw,
      (const f32x4*)x, (bf16x4*)ws,
      idx, wts, tok_id, tok_w, dst_id, cnts, offs, tiles);
  // gateup GEMM + overlapped dwn/sdw cast (appended grid rows)
  gateup_kernel<<<dim3(32, MAXTILES + CASTY), 256, 0, stream>>>(
      xb, wbg, wbu, act, tok_id, cnts, offs, tiles,
      (const f32x4*)dwn, (const f32x4*)sdw, (bf16x4*)ws);
  down_kernel<<<dim3(16, MAXTILES), 256, 0, stream>>>(
      act, wbd, buf, tok_w, dst_id, cnts, offs, tiles);
  combine_kernel<<<4096, 256, 0, stream>>>((const float4*)buf, (float4*)out);
}